// Round 4
// baseline (240.094 us; speedup 1.0000x reference)
//
#include <hip/hip_runtime.h>

typedef float f32x4 __attribute__((ext_vector_type(4)));

#define B_  8
#define C_  64
#define H_  256
#define W_  256
#define REP_ 512

// Streaming depthwise 3x3, fused dynamic-kernel taps.
//  - 1024 blocks = 512 planes x 2 half-planes; 4 waves/block, 32 rows/wave.
//  - per-wave ROLLED loop (4 x unroll-8): issue row j+5, prep j+2,
//    compute+store row j. Ring of 8 rows, &7 indices constant-fold in the
//    unrolled body. Steady state: 3 loads continuously in flight per wave,
//    phases desynchronize across waves (vs the burst kernels of r0-r3 that
//    all pinned at ~81us / 2.6 TB/s).
//  - taps computed per-block into LDS (wkey is L2-resident; ~18KB/block).

#define RING 8
#define RPW  32

__global__ __launch_bounds__(256) void dwconv3x3_stream(const float* __restrict__ x,
                                                        const float* __restrict__ rep,
                                                        const float* __restrict__ wkey,
                                                        float* __restrict__ out) {
    int plane = blockIdx.x >> 1;            // b*64 + c   (2 blocks per plane)
    int half  = blockIdx.x & 1;             // 128-row half of the plane
    int wv   = threadIdx.x >> 6;            // wave id within block
    int lane = threadIdx.x & 63;
    int b = plane >> 6;
    int c = plane & 63;

    // ---- phase 0: this plane's 9 kernel taps ----
    __shared__ float kk[9];
    const float* rrow = rep + (size_t)b * REP_;
    for (int i = wv; i < 9; i += 4) {
        const float* wrow = wkey + (size_t)(c * 9 + i) * REP_;
        float acc = 0.f;
#pragma unroll
        for (int t = 0; t < REP_ / 64; ++t)
            acc += rrow[lane + t * 64] * wrow[lane + t * 64];
#pragma unroll
        for (int off = 32; off > 0; off >>= 1)
            acc += __shfl_xor(acc, off, 64);
        if (lane == 0)
            kk[i] = acc > 0.f ? acc : 0.1f * acc;          // LeakyReLU(0.1)
    }
    __syncthreads();

    float k[9];
#pragma unroll
    for (int i = 0; i < 9; ++i) k[i] = kk[i];              // block-uniform

    // ---- streaming conv over this wave's 32-row band ----
    int r0 = half * 128 + wv * RPW;         // first output row
    int c4 = lane << 2;                     // this lane's 4 columns

    const float* pin  = x   + (size_t)plane * (H_ * W_);
    float*       pout = out + (size_t)plane * (H_ * W_);

    f32x4 raw[RING];
    float lft[RING], rgt[RING];

    // input row i (absolute t = r0-1+i) -> ring slot i&7
    auto issue = [&](int i) {
        int t = r0 - 1 + i;
        int rr = (t < 0) ? -t : ((t >= H_) ? (2 * H_ - 2 - t) : t);  // reflect
        raw[i & 7] = *(const f32x4*)(pin + (size_t)rr * W_ + c4);
    };
    auto prep = [&](int i) {
        int s = i & 7;
        float lv = __shfl(raw[s][3], lane - 1, 64);
        lft[s] = (lane == 0) ? raw[s][1] : lv;            // col -1 -> col 1
        float rv = __shfl(raw[s][0], lane + 1, 64);
        rgt[s] = (lane == 63) ? raw[s][2] : rv;           // col 256 -> col 254
    };
    auto e = [&](int i, int t) -> float {
        int s = i & 7;
        if (t == 0) return lft[s];
        if (t == 5) return rgt[s];
        return raw[s][t - 1];
    };

    // prologue: 5 loads in flight, first two rows prepped
#pragma unroll
    for (int i = 0; i < 5; ++i) issue(i);
    prep(0);
    prep(1);

    // steady state: ROLLED outer loop (do not let the compiler re-burst it)
#pragma unroll 1
    for (int it = 0; it < RPW / 8; ++it) {
#pragma unroll
        for (int u = 0; u < 8; ++u) {
            int j = it * 8 + u;             // (j+c)&7 == (u+c)&7: folds static
            issue(j + 5);                   // keep 3 loads in flight
            prep(j + 2);
            f32x4 o4;
#pragma unroll
            for (int t = 0; t < 4; ++t) {
                o4[t] = k[0] * e(j, t)     + k[1] * e(j, t + 1)     + k[2] * e(j, t + 2)
                      + k[3] * e(j + 1, t) + k[4] * e(j + 1, t + 1) + k[5] * e(j + 1, t + 2)
                      + k[6] * e(j + 2, t) + k[7] * e(j + 2, t + 1) + k[8] * e(j + 2, t + 2);
            }
            __builtin_nontemporal_store(o4, (f32x4*)(pout + (size_t)(r0 + j) * W_ + c4));
        }
    }
}

extern "C" void kernel_launch(void* const* d_in, const int* in_sizes, int n_in,
                              void* d_out, int out_size, void* d_ws, size_t ws_size,
                              hipStream_t stream) {
    const float* x    = (const float*)d_in[0];   // [8,64,256,256]
    const float* rep  = (const float*)d_in[1];   // [8,512]
    const float* wkey = (const float*)d_in[2];   // [576,512]
    float* out  = (float*)d_out;                 // [8,64,256,256]
    (void)d_ws; (void)ws_size;                   // workspace unused

    // 512 planes * 2 half-planes, 256 threads (4 waves x 32-row bands)
    dwconv3x3_stream<<<1024, 256, 0, stream>>>(x, rep, wkey, out);
}

// Round 6
// 235.274 us; speedup vs baseline: 1.0205x; 1.0205x over previous
//
#include <hip/hip_runtime.h>

typedef float f32x4 __attribute__((ext_vector_type(4)));

#define B_  8
#define C_  64
#define H_  256
#define W_  256
#define REP_ 512

#define BAND 32            // output rows per block
#define ROWS (BAND + 2)    // staged rows incl. halo

// LDS-staged depthwise 3x3 via async global_load_lds DMA.
//  - r0-r4 established: per-lane VGPR loads pin at 81-83us / 2.6 TB/s across
//    burst/ring/stream schedules and 4x TLP variation; VGPR counts (28-48)
//    prove the compiler collapses every source-level pipeline to ~2
//    outstanding loads/wave. global_load_lds needs NO destination registers,
//    so each wave issues its full 9KB staging burst back-to-back: ~34KB in
//    flight per block, ~136KB per CU. This is the untried mechanism.
__global__ __launch_bounds__(256) void dwconv3x3_lds(const float* __restrict__ x,
                                                     const float* __restrict__ rep,
                                                     const float* __restrict__ wkey,
                                                     float* __restrict__ out) {
    __shared__ float rows[ROWS][W_];   // 34 KB, linear (global_load_lds: no pad)
    __shared__ float kk[9];

    int plane = blockIdx.x >> 3;       // b*64 + c
    int band  = blockIdx.x & 7;        // 32-row band
    int wv   = threadIdx.x >> 6;
    int lane = threadIdx.x & 63;
    int b = plane >> 6;
    int c = plane & 63;

    const float* pin = x + (size_t)plane * (H_ * W_);

    // ---- phase 1: issue ALL staging DMAs first (traffic starts immediately;
    // no VGPR destinations -> nothing for the compiler to serialize on) ----
    {
        int t0 = band * BAND - 1;
        for (int i = wv; i < ROWS; i += 4) {           // 8-9 rows per wave
            int t = t0 + i;
            int rr = (t < 0) ? -t : ((t >= H_) ? (2 * H_ - 2 - t) : t);  // reflect
            const float* src = pin + (size_t)rr * W_ + lane * 4;   // lane*16 B
            __builtin_amdgcn_global_load_lds(
                (const __attribute__((address_space(1))) void*)src,
                (__attribute__((address_space(3))) void*)&rows[i][0],
                16, 0, 0);                              // wave: base + lane*16
        }
    }

    // ---- phase 2: taps (9 dot products), overlaps with DMAs in flight ----
    const float* rrow = rep + (size_t)b * REP_;
    for (int i = wv; i < 9; i += 4) {
        const float* wrow = wkey + (size_t)(c * 9 + i) * REP_;
        float acc = 0.f;
#pragma unroll
        for (int t = 0; t < REP_ / 64; ++t)
            acc += rrow[lane + t * 64] * wrow[lane + t * 64];
#pragma unroll
        for (int off = 32; off > 0; off >>= 1)
            acc += __shfl_xor(acc, off, 64);
        if (lane == 0)
            kk[i] = acc > 0.f ? acc : 0.1f * acc;      // LeakyReLU(0.1)
    }

    asm volatile("s_waitcnt vmcnt(0)" ::: "memory");   // DMAs + tap loads done
    __syncthreads();

    float k[9];
#pragma unroll
    for (int i = 0; i < 9; ++i) k[i] = kk[i];          // block-uniform

    // ---- phase 3: compute 8 rows per wave from LDS, store ----
    float* pout = out + (size_t)plane * (H_ * W_);
    int c4 = lane << 2;
    int jb = band * BAND + wv * 8;                     // first output row

#pragma unroll
    for (int u = 0; u < 8; ++u) {
        int li = wv * 8 + u;                           // top window row in LDS
        f32x4 m0 = *(const f32x4*)&rows[li][c4];
        f32x4 m1 = *(const f32x4*)&rows[li + 1][c4];
        f32x4 m2 = *(const f32x4*)&rows[li + 2][c4];
        // halo via neighbor-lane shuffle (no LDS bank conflicts, cheap VALU)
        float l0 = __shfl(m0[3], lane - 1, 64); l0 = (lane == 0) ? m0[1] : l0;
        float l1 = __shfl(m1[3], lane - 1, 64); l1 = (lane == 0) ? m1[1] : l1;
        float l2 = __shfl(m2[3], lane - 1, 64); l2 = (lane == 0) ? m2[1] : l2;
        float r0 = __shfl(m0[0], lane + 1, 64); r0 = (lane == 63) ? m0[2] : r0;
        float r1 = __shfl(m1[0], lane + 1, 64); r1 = (lane == 63) ? m1[2] : r1;
        float r2 = __shfl(m2[0], lane + 1, 64); r2 = (lane == 63) ? m2[2] : r2;

        auto E = [](const f32x4& m, float l, float r, int t) -> float {
            if (t == 0) return l;
            if (t == 5) return r;
            return m[t - 1];
        };
        f32x4 o4;
#pragma unroll
        for (int t = 0; t < 4; ++t) {
            o4[t] = k[0] * E(m0, l0, r0, t)     + k[1] * E(m0, l0, r0, t + 1) + k[2] * E(m0, l0, r0, t + 2)
                  + k[3] * E(m1, l1, r1, t)     + k[4] * E(m1, l1, r1, t + 1) + k[5] * E(m1, l1, r1, t + 2)
                  + k[6] * E(m2, l2, r2, t)     + k[7] * E(m2, l2, r2, t + 1) + k[8] * E(m2, l2, r2, t + 2);
        }
        __builtin_nontemporal_store(o4, (f32x4*)(pout + (size_t)(jb + u) * W_ + c4));
    }
}

extern "C" void kernel_launch(void* const* d_in, const int* in_sizes, int n_in,
                              void* d_out, int out_size, void* d_ws, size_t ws_size,
                              hipStream_t stream) {
    const float* x    = (const float*)d_in[0];   // [8,64,256,256]
    const float* rep  = (const float*)d_in[1];   // [8,512]
    const float* wkey = (const float*)d_in[2];   // [576,512]
    float* out  = (float*)d_out;                 // [8,64,256,256]
    (void)d_ws; (void)ws_size;                   // workspace unused

    // 512 planes * 8 bands, 256 threads (4 waves), 34 KB LDS -> 4 blocks/CU
    dwconv3x3_lds<<<4096, 256, 0, stream>>>(x, rep, wkey, out);
}